// Round 1
// baseline (236.201 us; speedup 1.0000x reference)
//
#include <hip/hip_runtime.h>
#include <stdint.h>

#define NN       20000
#define HID      128
#define TWO_MSG  128
#define NE       320000
#define GEPS     1e-10f

// ---------------- tiled fp32 GEMM: C[M,N] = A[M,K] @ B[N,K]^T + bias ----------------
// A is synthesized per MODE (never materialized):
//   MODE_FEAT_H: A = [feat | h]          (K=256)  -> node logits
//   MODE_FEAT_C: A = [feat | c-bits]     (K=256)  -> gi (decode GEMM folded into B)
//   MODE_H:      A = h                   (K=128)  -> gh
#define BM 64
#define BN 64
#define BK 32
#define LDT 68   // padded LDS row stride (floats), keeps 16B alignment, breaks bank stride

enum { MODE_FEAT_H = 0, MODE_FEAT_C = 1, MODE_H = 2 };

template <int MODE>
__global__ __launch_bounds__(256) void gemm_k(
    const float* __restrict__ feat, const float* __restrict__ hbuf,
    const unsigned long long* __restrict__ masks,  // [NN][2] = {any_zero, any_one}
    const float* __restrict__ B, const float* __restrict__ bias,
    float* __restrict__ C, int M, int N, int K)
{
    __shared__ float As[BK][LDT];
    __shared__ float Bs[BK][LDT];
    const int t  = threadIdx.x;
    const int m0 = blockIdx.y * BM;
    const int n0 = blockIdx.x * BN;
    const int tx = t & 15;
    const int ty = t >> 4;
    const int arow = t >> 2;        // 0..63
    const int ak0  = (t & 3) * 8;   // 0,8,16,24

    float acc[4][4];
#pragma unroll
    for (int i = 0; i < 4; ++i)
#pragma unroll
        for (int j = 0; j < 4; ++j) acc[i][j] = 0.f;

    for (int k0 = 0; k0 < K; k0 += BK) {
        // ---- stage A tile (transposed into [k][m]) ----
#pragma unroll
        for (int s = 0; s < 2; ++s) {
            const int kl = ak0 + s * 4;
            const int gm = m0 + arow;
            const int gk = k0 + kl;
            float v0 = 0.f, v1 = 0.f, v2 = 0.f, v3 = 0.f;
            if (gm < M) {
                if (MODE == MODE_H) {
                    const float4 f = *(const float4*)(hbuf + (size_t)gm * HID + gk);
                    v0 = f.x; v1 = f.y; v2 = f.z; v3 = f.w;
                } else if (gk < HID) {
                    const float4 f = *(const float4*)(feat + (size_t)gm * HID + gk);
                    v0 = f.x; v1 = f.y; v2 = f.z; v3 = f.w;
                } else if (MODE == MODE_FEAT_H) {
                    const float4 f = *(const float4*)(hbuf + (size_t)gm * HID + (gk - HID));
                    v0 = f.x; v1 = f.y; v2 = f.z; v3 = f.w;
                } else {  // MODE_FEAT_C: bits from masks
                    const unsigned long long mz = masks[(size_t)gm * 2 + 0];
                    const unsigned long long mo = masks[(size_t)gm * 2 + 1];
                    const int i0 = gk - HID;
                    v0 = (float)((((i0 + 0) & 1 ? mo : mz) >> ((i0 + 0) >> 1)) & 1ull);
                    v1 = (float)((((i0 + 1) & 1 ? mo : mz) >> ((i0 + 1) >> 1)) & 1ull);
                    v2 = (float)((((i0 + 2) & 1 ? mo : mz) >> ((i0 + 2) >> 1)) & 1ull);
                    v3 = (float)((((i0 + 3) & 1 ? mo : mz) >> ((i0 + 3) >> 1)) & 1ull);
                }
            }
            As[kl + 0][arow] = v0;
            As[kl + 1][arow] = v1;
            As[kl + 2][arow] = v2;
            As[kl + 3][arow] = v3;
        }
        // ---- stage B tile (transposed into [k][n]); N is always a multiple of 64 ----
#pragma unroll
        for (int s = 0; s < 2; ++s) {
            const int kl = ak0 + s * 4;
            const float4 f = *(const float4*)(B + (size_t)(n0 + arow) * K + k0 + kl);
            Bs[kl + 0][arow] = f.x;
            Bs[kl + 1][arow] = f.y;
            Bs[kl + 2][arow] = f.z;
            Bs[kl + 3][arow] = f.w;
        }
        __syncthreads();

#pragma unroll
        for (int kk = 0; kk < BK; ++kk) {
            const float4 a = *(const float4*)&As[kk][ty * 4];
            const float4 b = *(const float4*)&Bs[kk][tx * 4];
            const float av[4] = {a.x, a.y, a.z, a.w};
            const float bv[4] = {b.x, b.y, b.z, b.w};
#pragma unroll
            for (int i = 0; i < 4; ++i)
#pragma unroll
                for (int j = 0; j < 4; ++j) acc[i][j] += av[i] * bv[j];
        }
        __syncthreads();
    }

#pragma unroll
    for (int i = 0; i < 4; ++i) {
        const int gm = m0 + ty * 4 + i;
        if (gm < M) {
            const int gn = n0 + tx * 4;
            float4 o;
            o.x = acc[i][0] + bias[gn + 0];
            o.y = acc[i][1] + bias[gn + 1];
            o.z = acc[i][2] + bias[gn + 2];
            o.w = acc[i][3] + bias[gn + 3];
            *(float4*)(C + (size_t)gm * N + gn) = o;
        }
    }
}

// ---------------- prep: fold decode GEMM into gi weights ----------------
// Bcomb[o][k] = k<128 ? W_ih[o][k] : sum_j W_ih[o][128+j] * W_dec[j][k-128]
// bfold[o]    = b_ih[o] + sum_j W_ih[o][128+j] * b_dec[j]
__global__ __launch_bounds__(256) void prep_k(
    const float* __restrict__ W_ih, const float* __restrict__ W_dec,
    const float* __restrict__ b_ih, const float* __restrict__ b_dec,
    float* __restrict__ Bcomb, float* __restrict__ bfold)
{
    const int t = blockIdx.x * 256 + threadIdx.x;
    if (t >= 384 * 256) return;
    const int o = t >> 8;
    const int k = t & 255;
    float v;
    if (k < 128) {
        v = W_ih[(size_t)o * 256 + k];
    } else {
        const int i = k - 128;
        float s = 0.f;
        for (int j = 0; j < 128; ++j)
            s += W_ih[(size_t)o * 256 + 128 + j] * W_dec[(size_t)j * 128 + i];
        v = s;
    }
    Bcomb[(size_t)o * 256 + k] = v;
    if (k == 0) {
        float s = b_ih[o];
        for (int j = 0; j < 128; ++j)
            s += W_ih[(size_t)o * 256 + 128 + j] * b_dec[j];
        bfold[o] = s;
    }
}

// ---------------- edge kernel: one wave per edge ----------------
// decision bit k: (l1+g1) > (l0+g0); ballot -> two u64 masks; atomicOr into dst
__global__ __launch_bounds__(256) void edge_k(
    const float* __restrict__ u, const int* __restrict__ src,
    const int* __restrict__ dst, const float* __restrict__ logits,
    unsigned long long* __restrict__ masks)
{
    const int gid  = blockIdx.x * 256 + threadIdx.x;
    const int e    = gid >> 6;
    const int lane = gid & 63;
    if (e >= NE) return;
    const int s = src[e];
    const int d = dst[e];
    const float2 uu = *(const float2*)(u + (size_t)e * TWO_MSG + lane * 2);
    const float g0 = -logf(-logf(uu.x + GEPS) + GEPS);
    const float g1 = -logf(-logf(uu.y + GEPS) + GEPS);
    const float2 ll = *(const float2*)(logits + (size_t)s * TWO_MSG + lane * 2);
    const bool bit = (ll.y + g1) > (ll.x + g0);  // tie -> argmax picks index 0
    const unsigned long long mone = __ballot(bit);
    if (lane == 0) {
        atomicOr(&masks[(size_t)d * 2 + 1], mone);
        atomicOr(&masks[(size_t)d * 2 + 0], ~mone);
    }
}

// ---------------- gates: GRU elementwise + dual output write ----------------
__global__ __launch_bounds__(256) void gates_k(
    const float* __restrict__ gi, const float* __restrict__ gh,
    const float* __restrict__ h, float* __restrict__ out)
{
    const int t = blockIdx.x * 256 + threadIdx.x;
    if (t >= NN * HID) return;
    const int n = t >> 7;
    const int j = t & 127;
    const float* gin = gi + (size_t)n * 384;
    const float* ghn = gh + (size_t)n * 384;
    const float r  = 1.f / (1.f + expf(-(gin[j] + ghn[j])));
    const float z  = 1.f / (1.f + expf(-(gin[j + 128] + ghn[j + 128])));
    const float nn = tanhf(gin[j + 256] + r * ghn[j + 256]);
    const float hv = h[t];
    const float hnew = (1.f - z) * nn + z * hv;
    out[t] = hnew;
    out[t + NN * HID] = hnew;
}

extern "C" void kernel_launch(void* const* d_in, const int* in_sizes, int n_in,
                              void* d_out, int out_size, void* d_ws, size_t ws_size,
                              hipStream_t stream) {
    const float* feat  = (const float*)d_in[0];
    const float* h     = (const float*)d_in[1];
    const int*   src   = (const int*)d_in[2];
    const int*   dst   = (const int*)d_in[3];
    const float* u     = (const float*)d_in[4];
    const float* W_enc = (const float*)d_in[5];
    const float* b_enc = (const float*)d_in[6];
    const float* W_dec = (const float*)d_in[7];
    const float* b_dec = (const float*)d_in[8];
    const float* W_ih  = (const float*)d_in[9];
    const float* W_hh  = (const float*)d_in[10];
    const float* b_ih  = (const float*)d_in[11];
    const float* b_hh  = (const float*)d_in[12];
    float* out = (float*)d_out;

    // workspace layout (256B-aligned offsets)
    char* ws = (char*)d_ws;
    float*              logits = (float*)(ws + 0);                        // 20000*128 f32 = 10,240,000 B
    unsigned long long* masks  = (unsigned long long*)(ws + 10240000);    // 20000*2 u64  =    320,000 B
    float*              Bcomb  = (float*)(ws + 10560000);                 // 384*256 f32  =    393,216 B
    float*              bfold  = (float*)(ws + 10953216);                 // 384 f32      =      1,536 B
    float*              gi     = (float*)(ws + 10954752);                 // 20000*384    = 30,720,000 B
    float*              gh     = (float*)(ws + 41674752);                 // 20000*384    = 30,720,000 B
    (void)ws_size; (void)in_sizes; (void)n_in; (void)out_size;

    // zero the OR-aggregation masks (isolated nodes -> c = 0 automatically)
    hipMemsetAsync(masks, 0, (size_t)NN * 2 * sizeof(unsigned long long), stream);

    // fold decode weights into gi weights
    prep_k<<<384, 256, 0, stream>>>(W_ih, W_dec, b_ih, b_dec, Bcomb, bfold);

    // node logits: [feat|h] @ W_enc^T + b_enc   (M=20000, N=128, K=256)
    {
        dim3 grid(128 / BN, (NN + BM - 1) / BM);
        gemm_k<MODE_FEAT_H><<<grid, 256, 0, stream>>>(feat, h, nullptr, W_enc, b_enc,
                                                      logits, NN, 128, 256);
    }

    // per-edge gumbel argmax -> bit masks (1 wave / edge)
    edge_k<<<(NE * 64) / 256, 256, 0, stream>>>(u, src, dst, logits, masks);

    // gi = [feat | c] @ Bcomb^T + bfold   (M=20000, N=384, K=256)
    {
        dim3 grid(384 / BN, (NN + BM - 1) / BM);
        gemm_k<MODE_FEAT_C><<<grid, 256, 0, stream>>>(feat, nullptr, masks, Bcomb, bfold,
                                                      gi, NN, 384, 256);
    }

    // gh = h @ W_hh^T + b_hh   (M=20000, N=384, K=128)
    {
        dim3 grid(384 / BN, (NN + BM - 1) / BM);
        gemm_k<MODE_H><<<grid, 256, 0, stream>>>(nullptr, h, nullptr, W_hh, b_hh,
                                                 gh, NN, 384, 128);
    }

    // GRU gates + write (h_new, h_new)
    gates_k<<<(NN * HID) / 256, 256, 0, stream>>>(gi, gh, h, out);
}

// Round 2
// 187.135 us; speedup vs baseline: 1.2622x; 1.2622x over previous
//
#include <hip/hip_runtime.h>
#include <stdint.h>

#define NN   20000
#define HID  128
#define NE   320000
#define GEPS 1e-10f

// ======================= prep: fold weights =======================
// Bbig [384][256]: rows 0..127 = W_enc; rows 128..383 (o=row-128): [W_ih[o][0:128] | W_hh[o][0:128]]
// W_comb [384][128] = W_ih[:,128:256] @ W_dec
// bias_big[384]: 0..127 = b_enc; 128..383 (o): b_ih[o]+b_hh[o]+sum_j W_ih[o][128+j]*(b_dec[j]+rowsum W_dec[j])
// bias_inn[128]: b_ih[256+o] + sum_j W_ih[256+o][128+j]*(b_dec[j]+rowsum W_dec[j])
__global__ __launch_bounds__(256) void prep_k(
    const float* __restrict__ W_enc, const float* __restrict__ b_enc,
    const float* __restrict__ W_dec, const float* __restrict__ b_dec,
    const float* __restrict__ W_ih,  const float* __restrict__ W_hh,
    const float* __restrict__ b_ih,  const float* __restrict__ b_hh,
    float* __restrict__ Bbig, float* __restrict__ bias_big,
    float* __restrict__ W_comb, float* __restrict__ bias_inn)
{
    const int b = blockIdx.x, t = threadIdx.x;
    if (b < 384) {                 // Bbig fill
        const int idx = b * 256 + t;
        const int row = idx >> 8, k = idx & 255;
        float v;
        if (row < 128) v = W_enc[row * 256 + k];
        else {
            const int o = row - 128;
            v = (k < 128) ? W_ih[o * 256 + k] : W_hh[o * 128 + (k - 128)];
        }
        Bbig[idx] = v;
    } else if (b < 576) {          // W_comb
        const int idx = (b - 384) * 256 + t;
        const int o = idx >> 7, k = idx & 127;
        float s = 0.f;
        for (int j = 0; j < 128; ++j)
            s += W_ih[o * 256 + 128 + j] * W_dec[j * 128 + k];
        W_comb[idx] = s;
    } else {                       // biases (2 blocks)
        __shared__ float bd[128];
        if (t < 128) {
            float s = b_dec[t];
            for (int k = 0; k < 128; ++k) s += W_dec[t * 128 + k];
            bd[t] = s;
        }
        __syncthreads();
        const int g = (b - 576) * 256 + t;   // 0..511
        if (g < 384) {
            float v;
            if (g < 128) v = b_enc[g];
            else {
                const int o = g - 128;
                float s = b_ih[o] + b_hh[o];
                for (int j = 0; j < 128; ++j) s += W_ih[o * 256 + 128 + j] * bd[j];
                v = s;
            }
            bias_big[g] = v;
        } else {
            const int o = g - 384;
            float s = b_ih[256 + o];
            for (int j = 0; j < 128; ++j) s += W_ih[(256 + o) * 256 + 128 + j] * bd[j];
            bias_inn[o] = s;
        }
    }
}

// ======================= big GEMM =======================
// C[M=20000, N=384] = [feat|h] @ Bbig^T + bias_big, K=256.
// n-block 0 -> epilogue writes rtab[n][j] = exp(l[2j+1]-l[2j]) (no logits stored)
// n-blocks 1,2 -> rz_sum [20000][256]
__global__ __launch_bounds__(256) void gemm_big(
    const float* __restrict__ feat, const float* __restrict__ h,
    const float* __restrict__ Bbig, const float* __restrict__ bias,
    float* __restrict__ rtab, float* __restrict__ rz)
{
    __shared__ float As[16][132];
    __shared__ float Bs[16][132];
    const int t  = threadIdx.x;
    const int n0 = blockIdx.x * 128;
    const int m0 = blockIdx.y * 128;
    const int row = t >> 2, kc = (t & 3) * 4;
    const int ty = t >> 4, tx = t & 15;

    float acc[8][8];
#pragma unroll
    for (int i = 0; i < 8; ++i)
#pragma unroll
        for (int j = 0; j < 8; ++j) acc[i][j] = 0.f;

    for (int k0 = 0; k0 < 256; k0 += 16) {
        const float* Ab = (k0 < 128) ? feat : h;
        const int ko = k0 & 127;
#pragma unroll
        for (int c = 0; c < 2; ++c) {
            const int r = row + c * 64;
            float4 v = make_float4(0.f, 0.f, 0.f, 0.f);
            if (m0 + r < NN) v = *(const float4*)(Ab + (size_t)(m0 + r) * 128 + ko + kc);
            As[kc + 0][r] = v.x; As[kc + 1][r] = v.y; As[kc + 2][r] = v.z; As[kc + 3][r] = v.w;
        }
#pragma unroll
        for (int c = 0; c < 2; ++c) {
            const int r = row + c * 64;
            const float4 v = *(const float4*)(Bbig + (size_t)(n0 + r) * 256 + k0 + kc);
            Bs[kc + 0][r] = v.x; Bs[kc + 1][r] = v.y; Bs[kc + 2][r] = v.z; Bs[kc + 3][r] = v.w;
        }
        __syncthreads();
#pragma unroll
        for (int kk = 0; kk < 16; ++kk) {
            const float4 a0 = *(const float4*)&As[kk][ty * 4];
            const float4 a1 = *(const float4*)&As[kk][64 + ty * 4];
            const float4 b0 = *(const float4*)&Bs[kk][tx * 4];
            const float4 b1 = *(const float4*)&Bs[kk][64 + tx * 4];
            const float av[8] = {a0.x, a0.y, a0.z, a0.w, a1.x, a1.y, a1.z, a1.w};
            const float bv[8] = {b0.x, b0.y, b0.z, b0.w, b1.x, b1.y, b1.z, b1.w};
#pragma unroll
            for (int i = 0; i < 8; ++i)
#pragma unroll
                for (int j = 0; j < 8; ++j) acc[i][j] = fmaf(av[i], bv[j], acc[i][j]);
        }
        __syncthreads();
    }

    float bv0[4], bv1[4];
#pragma unroll
    for (int j = 0; j < 4; ++j) { bv0[j] = bias[n0 + tx * 4 + j]; bv1[j] = bias[n0 + 64 + tx * 4 + j]; }
#pragma unroll
    for (int i = 0; i < 8; ++i) {
        const int rm = (i < 4) ? (ty * 4 + i) : (64 + ty * 4 + i - 4);
        const int gm = m0 + rm;
        if (gm >= NN) continue;
        float c0[4], c1[4];
#pragma unroll
        for (int j = 0; j < 4; ++j) { c0[j] = acc[i][j] + bv0[j]; c1[j] = acc[i][j + 4] + bv1[j]; }
        if (n0 == 0) {
            float2 r0 = make_float2(expf(c0[1] - c0[0]), expf(c0[3] - c0[2]));
            float2 r1 = make_float2(expf(c1[1] - c1[0]), expf(c1[3] - c1[2]));
            *(float2*)(rtab + (size_t)gm * 64 + tx * 2) = r0;
            *(float2*)(rtab + (size_t)gm * 64 + 32 + tx * 2) = r1;
        } else {
            *(float4*)(rz + (size_t)gm * 256 + (n0 - 128) + tx * 4) = *(const float4*)c0;
            *(float4*)(rz + (size_t)gm * 256 + (n0 - 128) + 64 + tx * 4) = *(const float4*)c1;
        }
    }
}

// ======================= inn / hn GEMM =======================
// z=0: inn = feat @ W_ih[256:384, 0:128]^T + bias_inn   (K=128, ldb=256)
// z=1: hn  = h    @ W_hh[256:384, :]^T     + b_hh[256:] (K=128, ldb=128)
__global__ __launch_bounds__(256) void gemm_innhn(
    const float* __restrict__ feat, const float* __restrict__ h,
    const float* __restrict__ W_ih, const float* __restrict__ W_hh,
    const float* __restrict__ bias_inn, const float* __restrict__ b_hh,
    float* __restrict__ inn, float* __restrict__ hn)
{
    __shared__ float As[16][132];
    __shared__ float Bs[16][132];
    const int t = threadIdx.x;
    const int z = blockIdx.z;
    const int m0 = blockIdx.y * 128;
    const float* A   = z ? h : feat;
    const float* B   = z ? (W_hh + 256 * 128) : (W_ih + 256 * 256);
    const int    ldb = z ? 128 : 256;
    const float* bia = z ? (b_hh + 256) : bias_inn;
    float*       C   = z ? hn : inn;

    const int row = t >> 2, kc = (t & 3) * 4;
    const int ty = t >> 4, tx = t & 15;

    float acc[8][8];
#pragma unroll
    for (int i = 0; i < 8; ++i)
#pragma unroll
        for (int j = 0; j < 8; ++j) acc[i][j] = 0.f;

    for (int k0 = 0; k0 < 128; k0 += 16) {
#pragma unroll
        for (int c = 0; c < 2; ++c) {
            const int r = row + c * 64;
            float4 v = make_float4(0.f, 0.f, 0.f, 0.f);
            if (m0 + r < NN) v = *(const float4*)(A + (size_t)(m0 + r) * 128 + k0 + kc);
            As[kc + 0][r] = v.x; As[kc + 1][r] = v.y; As[kc + 2][r] = v.z; As[kc + 3][r] = v.w;
        }
#pragma unroll
        for (int c = 0; c < 2; ++c) {
            const int r = row + c * 64;
            const float4 v = *(const float4*)(B + (size_t)r * ldb + k0 + kc);
            Bs[kc + 0][r] = v.x; Bs[kc + 1][r] = v.y; Bs[kc + 2][r] = v.z; Bs[kc + 3][r] = v.w;
        }
        __syncthreads();
#pragma unroll
        for (int kk = 0; kk < 16; ++kk) {
            const float4 a0 = *(const float4*)&As[kk][ty * 4];
            const float4 a1 = *(const float4*)&As[kk][64 + ty * 4];
            const float4 b0 = *(const float4*)&Bs[kk][tx * 4];
            const float4 b1 = *(const float4*)&Bs[kk][64 + tx * 4];
            const float av[8] = {a0.x, a0.y, a0.z, a0.w, a1.x, a1.y, a1.z, a1.w};
            const float bv[8] = {b0.x, b0.y, b0.z, b0.w, b1.x, b1.y, b1.z, b1.w};
#pragma unroll
            for (int i = 0; i < 8; ++i)
#pragma unroll
                for (int j = 0; j < 8; ++j) acc[i][j] = fmaf(av[i], bv[j], acc[i][j]);
        }
        __syncthreads();
    }

    float bv0[4], bv1[4];
#pragma unroll
    for (int j = 0; j < 4; ++j) { bv0[j] = bia[tx * 4 + j]; bv1[j] = bia[64 + tx * 4 + j]; }
#pragma unroll
    for (int i = 0; i < 8; ++i) {
        const int rm = (i < 4) ? (ty * 4 + i) : (64 + ty * 4 + i - 4);
        const int gm = m0 + rm;
        if (gm >= NN) continue;
        float c0[4], c1[4];
#pragma unroll
        for (int j = 0; j < 4; ++j) { c0[j] = acc[i][j] + bv0[j]; c1[j] = acc[i][j + 4] + bv1[j]; }
        *(float4*)(C + (size_t)gm * 128 + tx * 4) = *(const float4*)c0;
        *(float4*)(C + (size_t)gm * 128 + 64 + tx * 4) = *(const float4*)c1;
    }
}

// ======================= edge kernel =======================
// bit j: (l1+g1)>(l0+g0)  <=>  r*a0 > a1, a = eps - log(u+eps), r = exp(l1-l0)
__global__ __launch_bounds__(256) void edge_k(
    const float* __restrict__ u, const int* __restrict__ src,
    const int* __restrict__ dst, const float* __restrict__ rtab,
    unsigned long long* __restrict__ masks)
{
    const int e = __builtin_amdgcn_readfirstlane(blockIdx.x * 4 + (threadIdx.x >> 6));
    const int lane = threadIdx.x & 63;
    const int s = src[e];
    const int d = dst[e];
    const float2 uu = *(const float2*)(u + (size_t)e * 128 + lane * 2);
    const float r  = rtab[(size_t)s * 64 + lane];
    const float a0 = GEPS - logf(uu.x + GEPS);
    const float a1 = GEPS - logf(uu.y + GEPS);
    const unsigned long long mone = __ballot(r * a0 > a1);
    if (lane == 0) {
        atomicOr(&masks[(size_t)d * 2 + 1], mone);
        atomicOr(&masks[(size_t)d * 2 + 0], ~mone);
    }
}

// ======================= sparse correction =======================
// For every zero bit k of c[node]: rz/inn -= W_comb[col][k]. ~96% of blocks exit immediately.
__global__ __launch_bounds__(384) void corr_k(
    const unsigned long long* __restrict__ masks, const float* __restrict__ W_comb,
    float* __restrict__ rz, float* __restrict__ inn)
{
    const int node = blockIdx.x;
    const unsigned long long mz = masks[(size_t)node * 2 + 0];
    const unsigned long long mo = masks[(size_t)node * 2 + 1];
    unsigned long long ze = ~mz, zo = ~mo;
    if ((ze | zo) == 0ull) return;
    const int col = threadIdx.x;          // 0..383
    float s = 0.f;
    unsigned long long b = ze;
    while (b) { const int j = __builtin_ctzll(b); b &= b - 1; s += W_comb[col * 128 + 2 * j]; }
    b = zo;
    while (b) { const int j = __builtin_ctzll(b); b &= b - 1; s += W_comb[col * 128 + 2 * j + 1]; }
    if (col < 256) rz[(size_t)node * 256 + col] -= s;
    else           inn[(size_t)node * 128 + (col - 256)] -= s;
}

// ======================= gates =======================
__global__ __launch_bounds__(256) void gates_k(
    const float* __restrict__ rz, const float* __restrict__ inn,
    const float* __restrict__ hn, const float* __restrict__ h,
    float* __restrict__ out)
{
    const int t = blockIdx.x * 256 + threadIdx.x;   // one float4 per thread
    const int n = t >> 5;
    const int j0 = (t & 31) * 4;
    if (n >= NN) return;
    const float4 vr = *(const float4*)(rz  + (size_t)n * 256 + j0);
    const float4 vz = *(const float4*)(rz  + (size_t)n * 256 + 128 + j0);
    const float4 vi = *(const float4*)(inn + (size_t)n * 128 + j0);
    const float4 vh = *(const float4*)(hn  + (size_t)n * 128 + j0);
    const float4 hv = *(const float4*)(h   + (size_t)n * 128 + j0);
    const float rr[4] = {vr.x, vr.y, vr.z, vr.w};
    const float zz[4] = {vz.x, vz.y, vz.z, vz.w};
    const float ii[4] = {vi.x, vi.y, vi.z, vi.w};
    const float hh[4] = {vh.x, vh.y, vh.z, vh.w};
    const float ho[4] = {hv.x, hv.y, hv.z, hv.w};
    float o[4];
#pragma unroll
    for (int q = 0; q < 4; ++q) {
        const float r = 1.f / (1.f + expf(-rr[q]));
        const float z = 1.f / (1.f + expf(-zz[q]));
        const float nval = tanhf(ii[q] + r * hh[q]);
        o[q] = (1.f - z) * nval + z * ho[q];
    }
    float4* o4 = (float4*)o;
    *(float4*)(out + (size_t)n * 128 + j0) = *o4;
    *(float4*)(out + (size_t)(NN + n) * 128 + j0) = *o4;
}

extern "C" void kernel_launch(void* const* d_in, const int* in_sizes, int n_in,
                              void* d_out, int out_size, void* d_ws, size_t ws_size,
                              hipStream_t stream) {
    const float* feat  = (const float*)d_in[0];
    const float* h     = (const float*)d_in[1];
    const int*   src   = (const int*)d_in[2];
    const int*   dst   = (const int*)d_in[3];
    const float* u     = (const float*)d_in[4];
    const float* W_enc = (const float*)d_in[5];
    const float* b_enc = (const float*)d_in[6];
    const float* W_dec = (const float*)d_in[7];
    const float* b_dec = (const float*)d_in[8];
    const float* W_ih  = (const float*)d_in[9];
    const float* W_hh  = (const float*)d_in[10];
    const float* b_ih  = (const float*)d_in[11];
    const float* b_hh  = (const float*)d_in[12];
    float* out = (float*)d_out;
    (void)in_sizes; (void)n_in; (void)out_size; (void)ws_size;

    char* ws = (char*)d_ws;
    float*              rtab     = (float*)(ws + 0);                   //  5,120,000 B
    unsigned long long* masks    = (unsigned long long*)(ws + 5120000);//    320,000 B
    float*              Bbig     = (float*)(ws + 5440000);             //    393,216 B
    float*              bias_big = (float*)(ws + 5833216);             //      2,048 B
    float*              W_comb   = (float*)(ws + 5835264);             //    196,608 B
    float*              bias_inn = (float*)(ws + 6031872);             //      1,024 B
    float*              rz       = (float*)(ws + 6032896);             // 20,480,000 B
    float*              inn      = (float*)(ws + 26512896);            // 10,240,000 B
    float*              hn       = (float*)(ws + 36752896);            // 10,240,000 B

    hipMemsetAsync(masks, 0, (size_t)NN * 2 * sizeof(unsigned long long), stream);

    prep_k<<<578, 256, 0, stream>>>(W_enc, b_enc, W_dec, b_dec, W_ih, W_hh, b_ih, b_hh,
                                    Bbig, bias_big, W_comb, bias_inn);

    {   // [feat|h] @ Bbig^T : N=384 (rtab + rz), K=256
        dim3 grid(3, (NN + 127) / 128);
        gemm_big<<<grid, 256, 0, stream>>>(feat, h, Bbig, bias_big, rtab, rz);
    }

    edge_k<<<NE / 4, 256, 0, stream>>>(u, src, dst, rtab, masks);

    {   // inn & hn, K=128
        dim3 grid(1, (NN + 127) / 128, 2);
        gemm_innhn<<<grid, 256, 0, stream>>>(feat, h, W_ih, W_hh, bias_inn, b_hh, inn, hn);
    }

    corr_k<<<NN, 384, 0, stream>>>(masks, W_comb, rz, inn);

    gates_k<<<(NN * 32 + 255) / 256, 256, 0, stream>>>(rz, inn, hn, h, out);
}

// Round 5
// 158.277 us; speedup vs baseline: 1.4923x; 1.1823x over previous
//
#include <hip/hip_runtime.h>
#include <stdint.h>

#define NN   20000
#define HID  128
#define NE   320000
#define GEPS 1e-10f

// ======================= prep: fold weights =======================
// Bbig [384][256]: rows 0..127 = W_enc; rows 128..383 (o=row-128): [W_ih[o][0:128] | W_hh[o][0:128]]
// W_comb [384][128] = W_ih[:,128:256] @ W_dec
// bias_big[384]: 0..127 = b_enc; 128..383 (o): b_ih[o]+b_hh[o]+sum_j W_ih[o][128+j]*(b_dec[j]+rowsum W_dec[j])
// bias_inn[128]: b_ih[256+o] + sum_j W_ih[256+o][128+j]*(b_dec[j]+rowsum W_dec[j])
__global__ __launch_bounds__(256) void prep_k(
    const float* __restrict__ W_enc, const float* __restrict__ b_enc,
    const float* __restrict__ W_dec, const float* __restrict__ b_dec,
    const float* __restrict__ W_ih,  const float* __restrict__ W_hh,
    const float* __restrict__ b_ih,  const float* __restrict__ b_hh,
    float* __restrict__ Bbig, float* __restrict__ bias_big,
    float* __restrict__ W_comb, float* __restrict__ bias_inn)
{
    const int b = blockIdx.x, t = threadIdx.x;
    if (b < 384) {                 // Bbig fill
        const int idx = b * 256 + t;
        const int row = idx >> 8, k = idx & 255;
        float v;
        if (row < 128) v = W_enc[row * 256 + k];
        else {
            const int o = row - 128;
            v = (k < 128) ? W_ih[o * 256 + k] : W_hh[o * 128 + (k - 128)];
        }
        Bbig[idx] = v;
    } else if (b < 576) {          // W_comb
        const int idx = (b - 384) * 256 + t;
        const int o = idx >> 7, k = idx & 127;
        float s = 0.f;
        for (int j = 0; j < 128; ++j)
            s += W_ih[o * 256 + 128 + j] * W_dec[j * 128 + k];
        W_comb[idx] = s;
    } else {                       // biases (2 blocks)
        __shared__ float bd[128];
        if (t < 128) {
            float s = b_dec[t];
            for (int k = 0; k < 128; ++k) s += W_dec[t * 128 + k];
            bd[t] = s;
        }
        __syncthreads();
        const int g = (b - 576) * 256 + t;   // 0..511
        if (g < 384) {
            float v;
            if (g < 128) v = b_enc[g];
            else {
                const int o = g - 128;
                float s = b_ih[o] + b_hh[o];
                for (int j = 0; j < 128; ++j) s += W_ih[o * 256 + 128 + j] * bd[j];
                v = s;
            }
            bias_big[g] = v;
        } else {
            const int o = g - 384;
            float s = b_ih[256 + o];
            for (int j = 0; j < 128; ++j) s += W_ih[(256 + o) * 256 + 128 + j] * bd[j];
            bias_inn[o] = s;
        }
    }
}

// ======================= big GEMM =======================
// C[M=20000, N=384] = [feat|h] @ Bbig^T + bias_big, K=256.
// n-block 0 -> epilogue writes rtab[n][j] = exp(l[2j+1]-l[2j]) (no logits stored)
// n-blocks 1,2 -> rz_sum [20000][256]
__global__ __launch_bounds__(256) void gemm_big(
    const float* __restrict__ feat, const float* __restrict__ h,
    const float* __restrict__ Bbig, const float* __restrict__ bias,
    float* __restrict__ rtab, float* __restrict__ rz)
{
    __shared__ float As[16][132];
    __shared__ float Bs[16][132];
    const int t  = threadIdx.x;
    const int n0 = blockIdx.x * 128;
    const int m0 = blockIdx.y * 128;
    const int row = t >> 2, kc = (t & 3) * 4;
    const int ty = t >> 4, tx = t & 15;

    float acc[8][8];
#pragma unroll
    for (int i = 0; i < 8; ++i)
#pragma unroll
        for (int j = 0; j < 8; ++j) acc[i][j] = 0.f;

    for (int k0 = 0; k0 < 256; k0 += 16) {
        const float* Ab = (k0 < 128) ? feat : h;
        const int ko = k0 & 127;
#pragma unroll
        for (int c = 0; c < 2; ++c) {
            const int r = row + c * 64;
            float4 v = make_float4(0.f, 0.f, 0.f, 0.f);
            if (m0 + r < NN) v = *(const float4*)(Ab + (size_t)(m0 + r) * 128 + ko + kc);
            As[kc + 0][r] = v.x; As[kc + 1][r] = v.y; As[kc + 2][r] = v.z; As[kc + 3][r] = v.w;
        }
#pragma unroll
        for (int c = 0; c < 2; ++c) {
            const int r = row + c * 64;
            const float4 v = *(const float4*)(Bbig + (size_t)(n0 + r) * 256 + k0 + kc);
            Bs[kc + 0][r] = v.x; Bs[kc + 1][r] = v.y; Bs[kc + 2][r] = v.z; Bs[kc + 3][r] = v.w;
        }
        __syncthreads();
#pragma unroll
        for (int kk = 0; kk < 16; ++kk) {
            const float4 a0 = *(const float4*)&As[kk][ty * 4];
            const float4 a1 = *(const float4*)&As[kk][64 + ty * 4];
            const float4 b0 = *(const float4*)&Bs[kk][tx * 4];
            const float4 b1 = *(const float4*)&Bs[kk][64 + tx * 4];
            const float av[8] = {a0.x, a0.y, a0.z, a0.w, a1.x, a1.y, a1.z, a1.w};
            const float bv[8] = {b0.x, b0.y, b0.z, b0.w, b1.x, b1.y, b1.z, b1.w};
#pragma unroll
            for (int i = 0; i < 8; ++i)
#pragma unroll
                for (int j = 0; j < 8; ++j) acc[i][j] = fmaf(av[i], bv[j], acc[i][j]);
        }
        __syncthreads();
    }

    float bv0[4], bv1[4];
#pragma unroll
    for (int j = 0; j < 4; ++j) { bv0[j] = bias[n0 + tx * 4 + j]; bv1[j] = bias[n0 + 64 + tx * 4 + j]; }
#pragma unroll
    for (int i = 0; i < 8; ++i) {
        const int rm = (i < 4) ? (ty * 4 + i) : (64 + ty * 4 + i - 4);
        const int gm = m0 + rm;
        if (gm >= NN) continue;
        float c0[4], c1[4];
#pragma unroll
        for (int j = 0; j < 4; ++j) { c0[j] = acc[i][j] + bv0[j]; c1[j] = acc[i][j + 4] + bv1[j]; }
        if (n0 == 0) {
            float2 r0 = make_float2(expf(c0[1] - c0[0]), expf(c0[3] - c0[2]));
            float2 r1 = make_float2(expf(c1[1] - c1[0]), expf(c1[3] - c1[2]));
            *(float2*)(rtab + (size_t)gm * 64 + tx * 2) = r0;
            *(float2*)(rtab + (size_t)gm * 64 + 32 + tx * 2) = r1;
        } else {
            *(float4*)(rz + (size_t)gm * 256 + (n0 - 128) + tx * 4) = *(const float4*)c0;
            *(float4*)(rz + (size_t)gm * 256 + (n0 - 128) + 64 + tx * 4) = *(const float4*)c1;
        }
    }
}

// ======================= inn / hn GEMM =======================
__global__ __launch_bounds__(256) void gemm_innhn(
    const float* __restrict__ feat, const float* __restrict__ h,
    const float* __restrict__ W_ih, const float* __restrict__ W_hh,
    const float* __restrict__ bias_inn, const float* __restrict__ b_hh,
    float* __restrict__ inn, float* __restrict__ hn)
{
    __shared__ float As[16][132];
    __shared__ float Bs[16][132];
    const int t = threadIdx.x;
    const int z = blockIdx.z;
    const int m0 = blockIdx.y * 128;
    const float* A   = z ? h : feat;
    const float* B   = z ? (W_hh + 256 * 128) : (W_ih + 256 * 256);
    const int    ldb = z ? 128 : 256;
    const float* bia = z ? (b_hh + 256) : bias_inn;
    float*       C   = z ? hn : inn;

    const int row = t >> 2, kc = (t & 3) * 4;
    const int ty = t >> 4, tx = t & 15;

    float acc[8][8];
#pragma unroll
    for (int i = 0; i < 8; ++i)
#pragma unroll
        for (int j = 0; j < 8; ++j) acc[i][j] = 0.f;

    for (int k0 = 0; k0 < 128; k0 += 16) {
#pragma unroll
        for (int c = 0; c < 2; ++c) {
            const int r = row + c * 64;
            float4 v = make_float4(0.f, 0.f, 0.f, 0.f);
            if (m0 + r < NN) v = *(const float4*)(A + (size_t)(m0 + r) * 128 + k0 + kc);
            As[kc + 0][r] = v.x; As[kc + 1][r] = v.y; As[kc + 2][r] = v.z; As[kc + 3][r] = v.w;
        }
#pragma unroll
        for (int c = 0; c < 2; ++c) {
            const int r = row + c * 64;
            const float4 v = *(const float4*)(B + (size_t)r * ldb + k0 + kc);
            Bs[kc + 0][r] = v.x; Bs[kc + 1][r] = v.y; Bs[kc + 2][r] = v.z; Bs[kc + 3][r] = v.w;
        }
        __syncthreads();
#pragma unroll
        for (int kk = 0; kk < 16; ++kk) {
            const float4 a0 = *(const float4*)&As[kk][ty * 4];
            const float4 a1 = *(const float4*)&As[kk][64 + ty * 4];
            const float4 b0 = *(const float4*)&Bs[kk][tx * 4];
            const float4 b1 = *(const float4*)&Bs[kk][64 + tx * 4];
            const float av[8] = {a0.x, a0.y, a0.z, a0.w, a1.x, a1.y, a1.z, a1.w};
            const float bv[8] = {b0.x, b0.y, b0.z, b0.w, b1.x, b1.y, b1.z, b1.w};
#pragma unroll
            for (int i = 0; i < 8; ++i)
#pragma unroll
                for (int j = 0; j < 8; ++j) acc[i][j] = fmaf(av[i], bv[j], acc[i][j]);
        }
        __syncthreads();
    }

    float bv0[4], bv1[4];
#pragma unroll
    for (int j = 0; j < 4; ++j) { bv0[j] = bia[tx * 4 + j]; bv1[j] = bia[64 + tx * 4 + j]; }
#pragma unroll
    for (int i = 0; i < 8; ++i) {
        const int rm = (i < 4) ? (ty * 4 + i) : (64 + ty * 4 + i - 4);
        const int gm = m0 + rm;
        if (gm >= NN) continue;
        float c0[4], c1[4];
#pragma unroll
        for (int j = 0; j < 4; ++j) { c0[j] = acc[i][j] + bv0[j]; c1[j] = acc[i][j + 4] + bv1[j]; }
        *(float4*)(C + (size_t)gm * 128 + tx * 4) = *(const float4*)c0;
        *(float4*)(C + (size_t)gm * 128 + 64 + tx * 4) = *(const float4*)c1;
    }
}

// ======================= edge kernel: 16 edges per wave =======================
// bit j: (l1+g1)>(l0+g0)  <=>  r*a0 > a1, a = eps - log(u+eps), r = exp(l1-l0)
// All 32 vector loads issued before any compute -> deep memory pipeline.
#define EPW 16
__global__ __launch_bounds__(256) void edge_k(
    const float* __restrict__ u, const int* __restrict__ src,
    const int* __restrict__ dst, const float* __restrict__ rtab,
    unsigned long long* __restrict__ masks)
{
    const int wv = __builtin_amdgcn_readfirstlane(blockIdx.x * 4 + (threadIdx.x >> 6));
    const int lane = threadIdx.x & 63;
    const int e0 = wv * EPW;

    float2 uu[EPW];
    float  rr[EPW];
    int    dd[EPW];
#pragma unroll
    for (int i = 0; i < EPW; ++i) {
        const int e = e0 + i;
        uu[i] = *(const float2*)(u + (size_t)e * 128 + lane * 2);
        rr[i] = rtab[(size_t)src[e] * 64 + lane];
        dd[i] = dst[e];
    }
#pragma unroll
    for (int i = 0; i < EPW; ++i) {
        const float a0 = GEPS - logf(uu[i].x + GEPS);
        const float a1 = GEPS - logf(uu[i].y + GEPS);
        const unsigned long long mone = __ballot(rr[i] * a0 > a1);
        if (lane == 0) {
            atomicOr(&masks[(size_t)dd[i] * 2 + 1], mone);
            atomicOr(&masks[(size_t)dd[i] * 2 + 0], ~mone);
        }
    }
}

// ======================= gates (with fused sparse correction) =======================
// rz/inn were computed with c == all-ones folded into bias; subtract W_comb columns
// for every ZERO bit of c (rare: ~e^-deg per slot; deg==0 nodes handled automatically).
__global__ __launch_bounds__(256) void gates_k(
    const float* __restrict__ rz, const float* __restrict__ inn,
    const float* __restrict__ hn, const float* __restrict__ h,
    const unsigned long long* __restrict__ masks, const float* __restrict__ W_comb,
    float* __restrict__ out)
{
    const int t = blockIdx.x * 256 + threadIdx.x;   // one float4 per thread
    const int n = t >> 5;
    const int j0 = (t & 31) * 4;
    if (n >= NN) return;

    float cr[4] = {0.f, 0.f, 0.f, 0.f};
    float cz[4] = {0.f, 0.f, 0.f, 0.f};
    float ci[4] = {0.f, 0.f, 0.f, 0.f};
    {
        unsigned long long ze = ~masks[(size_t)n * 2 + 0];
        unsigned long long zo = ~masks[(size_t)n * 2 + 1];
        if (ze | zo) {
#pragma unroll 1
            while (ze) {
                const int k = __builtin_ctzll(ze); ze &= ze - 1;
                const int bit = 2 * k;
#pragma unroll
                for (int q = 0; q < 4; ++q) {
                    cr[q] += W_comb[(j0 + q) * 128 + bit];
                    cz[q] += W_comb[(128 + j0 + q) * 128 + bit];
                    ci[q] += W_comb[(256 + j0 + q) * 128 + bit];
                }
            }
#pragma unroll 1
            while (zo) {
                const int k = __builtin_ctzll(zo); zo &= zo - 1;
                const int bit = 2 * k + 1;
#pragma unroll
                for (int q = 0; q < 4; ++q) {
                    cr[q] += W_comb[(j0 + q) * 128 + bit];
                    cz[q] += W_comb[(128 + j0 + q) * 128 + bit];
                    ci[q] += W_comb[(256 + j0 + q) * 128 + bit];
                }
            }
        }
    }

    const float4 vr = *(const float4*)(rz  + (size_t)n * 256 + j0);
    const float4 vz = *(const float4*)(rz  + (size_t)n * 256 + 128 + j0);
    const float4 vi = *(const float4*)(inn + (size_t)n * 128 + j0);
    const float4 vh = *(const float4*)(hn  + (size_t)n * 128 + j0);
    const float4 hv = *(const float4*)(h   + (size_t)n * 128 + j0);
    const float rr[4] = {vr.x, vr.y, vr.z, vr.w};
    const float zz[4] = {vz.x, vz.y, vz.z, vz.w};
    const float ii[4] = {vi.x, vi.y, vi.z, vi.w};
    const float hh[4] = {vh.x, vh.y, vh.z, vh.w};
    const float ho[4] = {hv.x, hv.y, hv.z, hv.w};
    float o[4];
#pragma unroll
    for (int q = 0; q < 4; ++q) {
        const float r = 1.f / (1.f + expf(-(rr[q] - cr[q])));
        const float z = 1.f / (1.f + expf(-(zz[q] - cz[q])));
        const float nval = tanhf((ii[q] - ci[q]) + r * hh[q]);
        o[q] = (1.f - z) * nval + z * ho[q];
    }
    float4* o4 = (float4*)o;
    *(float4*)(out + (size_t)n * 128 + j0) = *o4;
    *(float4*)(out + (size_t)(NN + n) * 128 + j0) = *o4;
}

extern "C" void kernel_launch(void* const* d_in, const int* in_sizes, int n_in,
                              void* d_out, int out_size, void* d_ws, size_t ws_size,
                              hipStream_t stream) {
    const float* feat  = (const float*)d_in[0];
    const float* h     = (const float*)d_in[1];
    const int*   src   = (const int*)d_in[2];
    const int*   dst   = (const int*)d_in[3];
    const float* u     = (const float*)d_in[4];
    const float* W_enc = (const float*)d_in[5];
    const float* b_enc = (const float*)d_in[6];
    const float* W_dec = (const float*)d_in[7];
    const float* b_dec = (const float*)d_in[8];
    const float* W_ih  = (const float*)d_in[9];
    const float* W_hh  = (const float*)d_in[10];
    const float* b_ih  = (const float*)d_in[11];
    const float* b_hh  = (const float*)d_in[12];
    float* out = (float*)d_out;
    (void)in_sizes; (void)n_in; (void)out_size; (void)ws_size;

    char* ws = (char*)d_ws;
    float*              rtab     = (float*)(ws + 0);                   //  5,120,000 B
    unsigned long long* masks    = (unsigned long long*)(ws + 5120000);//    320,000 B
    float*              Bbig     = (float*)(ws + 5440000);             //    393,216 B
    float*              bias_big = (float*)(ws + 5833216);             //      2,048 B
    float*              W_comb   = (float*)(ws + 5835264);             //    196,608 B
    float*              bias_inn = (float*)(ws + 6031872);             //      1,024 B
    float*              rz       = (float*)(ws + 6032896);             // 20,480,000 B
    float*              inn      = (float*)(ws + 26512896);            // 10,240,000 B
    float*              hn       = (float*)(ws + 36752896);            // 10,240,000 B

    hipMemsetAsync(masks, 0, (size_t)NN * 2 * sizeof(unsigned long long), stream);

    prep_k<<<578, 256, 0, stream>>>(W_enc, b_enc, W_dec, b_dec, W_ih, W_hh, b_ih, b_hh,
                                    Bbig, bias_big, W_comb, bias_inn);

    {   // [feat|h] @ Bbig^T : N=384 (rtab + rz), K=256
        dim3 grid(3, (NN + 127) / 128);
        gemm_big<<<grid, 256, 0, stream>>>(feat, h, Bbig, bias_big, rtab, rz);
    }

    edge_k<<<NE / (4 * EPW), 256, 0, stream>>>(u, src, dst, rtab, masks);

    {   // inn & hn, K=128
        dim3 grid(1, (NN + 127) / 128, 2);
        gemm_innhn<<<grid, 256, 0, stream>>>(feat, h, W_ih, W_hh, bias_inn, b_hh, inn, hn);
    }

    gates_k<<<(NN * 32 + 255) / 256, 256, 0, stream>>>(rz, inn, hn, h, masks, W_comb, out);
}